// Round 1
// baseline (154.531 us; speedup 1.0000x reference)
//
#include <hip/hip_runtime.h>
#include <hip/hip_bf16.h>

#define NN 65536
#define MM 1024
#define DD 256
#define KT 512   // GEMM K = 2*D  ([x^2 | x] concat)

#define BM 128
#define BN 128
#define BK 64

typedef __attribute__((ext_vector_type(4))) float f32x4;
typedef __attribute__((ext_vector_type(8))) short bf16x8;
typedef __attribute__((ext_vector_type(4))) short bf16x4;

typedef const __attribute__((address_space(1))) unsigned int* gp_t;
typedef __attribute__((address_space(3))) unsigned int* lp_t;

static __device__ __forceinline__ unsigned short f2bf(float f) {
    union { float f; unsigned u; } v; v.f = f;
    unsigned r = v.u + 0x7fffu + ((v.u >> 16) & 1u);
    return (unsigned short)(r >> 16);
}

// A[n][0:256] = bf16(x^2), A[n][256:512] = bf16(x)
__global__ void prep_a_kernel(const float* __restrict__ x, unsigned short* __restrict__ A) {
    int t = blockIdx.x * 256 + threadIdx.x;   // NN*32 threads, 8 elems each
    int n = t >> 5;
    int d0 = (t & 31) << 3;
    const float* xp = x + (size_t)n * DD + d0;
    float4 v0 = *(const float4*)xp;
    float4 v1 = *(const float4*)(xp + 4);
    float vals[8] = {v0.x, v0.y, v0.z, v0.w, v1.x, v1.y, v1.z, v1.w};
    bf16x8 xv, x2v;
#pragma unroll
    for (int i = 0; i < 8; ++i) {
        xv[i]  = (short)f2bf(vals[i]);
        x2v[i] = (short)f2bf(vals[i] * vals[i]);
    }
    *(bf16x8*)(A + (size_t)n * KT + d0)      = x2v;
    *(bf16x8*)(A + (size_t)n * KT + DD + d0) = xv;
}

// B[m][0:256] = bf16(1/cov), B[m][256:512] = bf16(-2*mu/cov); tmv[m] = sum mu^2/cov
__global__ void prep_b_kernel(const float* __restrict__ mu, const float* __restrict__ cov,
                              unsigned short* __restrict__ B, float* __restrict__ tmv) {
    int t = blockIdx.x * 256 + threadIdx.x;   // MM*64 threads: one wave per m
    int m = t >> 6, lane = t & 63;
    int d0 = lane << 2;
    float4 c = *(const float4*)(cov + (size_t)m * DD + d0);
    float4 u = *(const float4*)(mu + (size_t)m * DD + d0);
    float ic[4] = {1.f / c.x, 1.f / c.y, 1.f / c.z, 1.f / c.w};
    float uu[4] = {u.x, u.y, u.z, u.w};
    bf16x4 icv, mv;
    float part = 0.f;
#pragma unroll
    for (int i = 0; i < 4; ++i) {
        icv[i] = (short)f2bf(ic[i]);
        mv[i]  = (short)f2bf(-2.f * uu[i] * ic[i]);
        part += uu[i] * uu[i] * ic[i];
    }
    *(bf16x4*)(B + (size_t)m * KT + d0)      = icv;
    *(bf16x4*)(B + (size_t)m * KT + DD + d0) = mv;
#pragma unroll
    for (int off = 32; off >= 1; off >>= 1) part += __shfl_xor(part, off);
    if (lane == 0) tmv[m] = part;
}

// out[n][m] = exp(-0.5*(A@B^T + tmv[m]))
__global__ __launch_bounds__(256) void gemm_kernel(
        const unsigned short* __restrict__ A, const unsigned short* __restrict__ B,
        const float* __restrict__ tmv, float* __restrict__ out) {
    __shared__ unsigned short Al[BM * BK];
    __shared__ unsigned short Bl[BN * BK];
    int bid = blockIdx.x;
    int mt = bid & 7;          // M/BN = 8 col tiles; consecutive blocks share A panel
    int nt = bid >> 3;
    int tid = threadIdx.x;
    int wid = tid >> 6, lane = tid & 63;
    int wr = wid >> 1, wc = wid & 1;     // 2x2 waves, 64x64 each
    int row0 = nt * BM, col0 = mt * BN;

    f32x4 acc[4][4] = {};

    int lrow = lane >> 3;           // row within 8-row chunk
    int cb = (lane & 7) << 4;       // col byte within 128B row

    for (int kt = 0; kt < KT / BK; ++kt) {
        __syncthreads();
#pragma unroll
        for (int i = 0; i < 4; ++i) {
            int chunk = wid * 4 + i;               // 16 chunks of 1KB (8 rows x 128B)
            int r = (chunk << 3) + lrow;
            const char* ga = (const char*)A + ((size_t)(row0 + r) * KT + (size_t)kt * BK) * 2 + cb;
            __builtin_amdgcn_global_load_lds((gp_t)ga, (lp_t)((char*)Al + (chunk << 10)), 16, 0, 0);
            const char* gb = (const char*)B + ((size_t)(col0 + r) * KT + (size_t)kt * BK) * 2 + cb;
            __builtin_amdgcn_global_load_lds((gp_t)gb, (lp_t)((char*)Bl + (chunk << 10)), 16, 0, 0);
        }
        __syncthreads();
#pragma unroll
        for (int kk = 0; kk < 2; ++kk) {
            bf16x8 af[4], bfr[4];
            int kof = (kk << 5) + ((lane >> 4) << 3);
#pragma unroll
            for (int i = 0; i < 4; ++i) {
                int r = (wr << 6) + (i << 4) + (lane & 15);
                af[i] = *(const bf16x8*)&Al[r * BK + kof];
            }
#pragma unroll
            for (int j = 0; j < 4; ++j) {
                int r = (wc << 6) + (j << 4) + (lane & 15);
                bfr[j] = *(const bf16x8*)&Bl[r * BK + kof];
            }
#pragma unroll
            for (int i = 0; i < 4; ++i)
#pragma unroll
                for (int j = 0; j < 4; ++j)
                    acc[i][j] = __builtin_amdgcn_mfma_f32_16x16x32_bf16(af[i], bfr[j], acc[i][j], 0, 0, 0);
        }
    }

#pragma unroll
    for (int j = 0; j < 4; ++j) {
        int c = col0 + (wc << 6) + (j << 4) + (lane & 15);
        float tmc = tmv[c];
#pragma unroll
        for (int i = 0; i < 4; ++i) {
            int r = row0 + (wr << 6) + (i << 4) + ((lane >> 4) << 2);
#pragma unroll
            for (int q = 0; q < 4; ++q) {
                out[(size_t)(r + q) * MM + c] = __expf(-0.5f * (acc[i][j][q] + tmc));
            }
        }
    }
}

// ws-too-small safety net: naive fp32, correct but slow
__global__ void fallback_kernel(const float* __restrict__ x, const float* __restrict__ mu,
                                const float* __restrict__ cov, float* __restrict__ out) {
    __shared__ float xs[DD];
    int n = blockIdx.x;
    int tid = threadIdx.x;
    if (tid < 64) {
        float4 v = *(const float4*)(x + (size_t)n * DD + tid * 4);
        *(float4*)&xs[tid * 4] = v;
    }
    __syncthreads();
    for (int m = tid; m < MM; m += 256) {
        const float* mup = mu + (size_t)m * DD;
        const float* cvp = cov + (size_t)m * DD;
        float acc = 0.f;
        for (int d = 0; d < DD; ++d) {
            float v = xs[d] - mup[d];
            acc += v * v * (1.0f / cvp[d]);
        }
        out[(size_t)n * MM + m] = __expf(-0.5f * acc);
    }
}

extern "C" void kernel_launch(void* const* d_in, const int* in_sizes, int n_in,
                              void* d_out, int out_size, void* d_ws, size_t ws_size,
                              hipStream_t stream) {
    const float* x   = (const float*)d_in[0];
    const float* mu  = (const float*)d_in[1];
    const float* cov = (const float*)d_in[2];
    float* out = (float*)d_out;

    size_t needA = (size_t)NN * KT * 2;   // 64 MB
    size_t needB = (size_t)MM * KT * 2;   // 1 MB
    size_t needT = (size_t)MM * 4;        // 4 KB
    if (ws_size < needA + needB + needT) {
        fallback_kernel<<<NN, 256, 0, stream>>>(x, mu, cov, out);
        return;
    }
    unsigned short* Ab = (unsigned short*)d_ws;
    unsigned short* Bb = (unsigned short*)((char*)d_ws + needA);
    float* tmv = (float*)((char*)d_ws + needA + needB);

    prep_a_kernel<<<NN * 32 / 256, 256, 0, stream>>>(x, Ab);
    prep_b_kernel<<<MM * 64 / 256, 256, 0, stream>>>(mu, cov, Bb, tmv);
    gemm_kernel<<<(NN / BM) * (MM / BN), 256, 0, stream>>>(Ab, Bb, tmv, out);
}

// Round 2
// 135.952 us; speedup vs baseline: 1.1367x; 1.1367x over previous
//
#include <hip/hip_runtime.h>
#include <hip/hip_bf16.h>

#define NN 65536
#define MM 1024
#define DD 256
#define KT 512   // GEMM K = 2*D ([x^2 | x] concat)

#define BM 256
#define BN 256
#define BK 64
#define NKT 8    // KT/BK

typedef __attribute__((ext_vector_type(4))) float f32x4;
typedef __attribute__((ext_vector_type(8))) short bf16x8;
typedef __attribute__((ext_vector_type(4))) short bf16x4;

typedef const __attribute__((address_space(1))) unsigned int* gp_t;
typedef __attribute__((address_space(3))) unsigned int* lp_t;

static __device__ __forceinline__ unsigned short f2bf(float f) {
    union { float f; unsigned u; } v; v.f = f;
    unsigned r = v.u + 0x7fffu + ((v.u >> 16) & 1u);
    return (unsigned short)(r >> 16);
}

// A[n][0:256] = bf16(x^2), A[n][256:512] = bf16(x)
__global__ void prep_a_kernel(const float* __restrict__ x, unsigned short* __restrict__ A) {
    int t = blockIdx.x * 256 + threadIdx.x;   // NN*32 threads, 8 elems each
    int n = t >> 5;
    int d0 = (t & 31) << 3;
    const float* xp = x + (size_t)n * DD + d0;
    float4 v0 = *(const float4*)xp;
    float4 v1 = *(const float4*)(xp + 4);
    float vals[8] = {v0.x, v0.y, v0.z, v0.w, v1.x, v1.y, v1.z, v1.w};
    bf16x8 xv, x2v;
#pragma unroll
    for (int i = 0; i < 8; ++i) {
        xv[i]  = (short)f2bf(vals[i]);
        x2v[i] = (short)f2bf(vals[i] * vals[i]);
    }
    *(bf16x8*)(A + (size_t)n * KT + d0)      = x2v;
    *(bf16x8*)(A + (size_t)n * KT + DD + d0) = xv;
}

// B[m][0:256] = bf16(1/cov), B[m][256:512] = bf16(-2*mu/cov); tmv[m] = sum mu^2/cov
__global__ void prep_b_kernel(const float* __restrict__ mu, const float* __restrict__ cov,
                              unsigned short* __restrict__ B, float* __restrict__ tmv) {
    int t = blockIdx.x * 256 + threadIdx.x;   // MM*64 threads: one wave per m
    int m = t >> 6, lane = t & 63;
    int d0 = lane << 2;
    float4 c = *(const float4*)(cov + (size_t)m * DD + d0);
    float4 u = *(const float4*)(mu + (size_t)m * DD + d0);
    float ic[4] = {1.f / c.x, 1.f / c.y, 1.f / c.z, 1.f / c.w};
    float uu[4] = {u.x, u.y, u.z, u.w};
    bf16x4 icv, mv;
    float part = 0.f;
#pragma unroll
    for (int i = 0; i < 4; ++i) {
        icv[i] = (short)f2bf(ic[i]);
        mv[i]  = (short)f2bf(-2.f * uu[i] * ic[i]);
        part += uu[i] * uu[i] * ic[i];
    }
    *(bf16x4*)(B + (size_t)m * KT + d0)      = icv;
    *(bf16x4*)(B + (size_t)m * KT + DD + d0) = mv;
#pragma unroll
    for (int off = 32; off >= 1; off >>= 1) part += __shfl_xor(part, off);
    if (lane == 0) tmv[m] = part;
}

// ---- 256x256 8-phase pipelined GEMM: out[n][m] = exp(-0.5*(A@B^T + tmv[m])) ----
// LDS: A double-buffered (2x32KB) + B triple-buffered (3x32KB) = 160 KiB.
// Per 4-phase group: issue 4 A-loads (ph1-2) then 4 B-loads (ph3-4);
// s_waitcnt vmcnt(4) at group end keeps 4 B-loads in flight across the barrier.
// LDS swizzle: stored[row][slot] = global[row][slot ^ (row&7)] (16B slots),
// applied on the global SOURCE address (gload_lds dest must be linear) and
// inverted on the ds_read side (involution).

#define BAR() do { asm volatile("" ::: "memory"); __builtin_amdgcn_s_barrier(); asm volatile("" ::: "memory"); } while (0)

// stage half-tile h (2 x global_load_lds, 64 rows each) of K-tile t
#define STAGE_A2(t, buf, h) do { \
    _Pragma("unroll") \
    for (int p_ = 2*(h); p_ < 2*(h) + 2; ++p_) \
        __builtin_amdgcn_global_load_lds( \
            (gp_t)(Abp + (size_t)(t) * (BK*2) + (size_t)(p_*64 + wid8g) * (KT*2)), \
            (lp_t)(&lds[(buf)*16384 + p_*4096 + widl]), 16, 0, 0); \
} while (0)

#define STAGE_B2(t, slot, h) do { \
    _Pragma("unroll") \
    for (int p_ = 2*(h); p_ < 2*(h) + 2; ++p_) \
        __builtin_amdgcn_global_load_lds( \
            (gp_t)(Bbp + (size_t)(t) * (BK*2) + (size_t)(p_*64 + wid8g) * (KT*2)), \
            (lp_t)(&lds[32768 + (slot)*16384 + p_*4096 + widl]), 16, 0, 0); \
} while (0)

// ushort-index LDS reads (keeps addrspace(3) inference -> ds_read_b128)
#define READ_A4(dst, abu, ibase) do { \
    _Pragma("unroll") \
    for (int ii_ = 0; ii_ < 4; ++ii_) { \
        dst[ii_][0] = *(const bf16x8*)&lds[(abu) + arow_u + ((ibase) + ii_) * 1024 + sa0u]; \
        dst[ii_][1] = *(const bf16x8*)&lds[(abu) + arow_u + ((ibase) + ii_) * 1024 + sa1u]; \
    } \
} while (0)

#define READ_B2(dst, bbu, jbase) do { \
    _Pragma("unroll") \
    for (int jj_ = 0; jj_ < 2; ++jj_) { \
        dst[jj_][0] = *(const bf16x8*)&lds[(bbu) + brow_u + ((jbase) + jj_) * 1024 + sa0u]; \
        dst[jj_][1] = *(const bf16x8*)&lds[(bbu) + brow_u + ((jbase) + jj_) * 1024 + sa1u]; \
    } \
} while (0)

#define MFMA16(Af, Bf, ib, jb) do { \
    __builtin_amdgcn_s_setprio(1); \
    _Pragma("unroll") \
    for (int kk_ = 0; kk_ < 2; ++kk_) \
    _Pragma("unroll") \
    for (int ii_ = 0; ii_ < 4; ++ii_) \
    _Pragma("unroll") \
    for (int jj_ = 0; jj_ < 2; ++jj_) \
        acc[(ib)+ii_][(jb)+jj_] = __builtin_amdgcn_mfma_f32_16x16x32_bf16( \
            Af[ii_][kk_], Bf[jj_][kk_], acc[(ib)+ii_][(jb)+jj_], 0, 0, 0); \
    __builtin_amdgcn_s_setprio(0); \
} while (0)

// 4 phases over one K-tile; S1..S4 = staging stmts, VML = vmcnt wait stmt
#define KTILE(abu, bbu, S1, S2, S3, S4, VML) do { \
    bf16x8 a0_[4][2], a1_[4][2], b0_[2][2], b1_[2][2]; \
    READ_A4(a0_, abu, 0); \
    READ_B2(b0_, bbu, 0); \
    S1; BAR(); MFMA16(a0_, b0_, 0, 0); BAR(); \
    READ_B2(b1_, bbu, 2); \
    S2; BAR(); MFMA16(a0_, b1_, 0, 2); BAR(); \
    READ_A4(a1_, abu, 4); \
    S3; BAR(); MFMA16(a1_, b1_, 4, 2); BAR(); \
    S4; VML; BAR(); MFMA16(a1_, b0_, 4, 0); BAR(); \
} while (0)

__global__ __launch_bounds__(512, 2) void gemm_kernel(
        const unsigned short* __restrict__ A, const unsigned short* __restrict__ B,
        const float* __restrict__ tmv, float* __restrict__ out) {
    __shared__ __align__(16) unsigned short lds[81920];   // 160 KiB

    int tid = threadIdx.x;
    int wid = tid >> 6, lane = tid & 63;
    int wr = wid >> 2, wc = wid & 3;       // 2x4 waves, each 128x64 of C
    int lr = lane & 15, kg = lane >> 4;

    // T1: XCD-aware swizzle (1024 blocks % 8 == 0 -> bijective); mt inner so
    // the 4 col-tiles sharing an A panel are L2-adjacent on one XCD.
    int bid = blockIdx.x;
    int wg = (bid & 7) * 128 + (bid >> 3);
    int nt = wg >> 2, mt = wg & 3;
    int row0 = nt * BM, col0 = mt * BN;

    // staging constants: instr p covers rows p*64 + wid*8 + (lane>>3)
    int grow = lane >> 3;
    int wid8g = wid * 8 + grow;
    int widl = wid * 512;                         // ushort offset of wave chunk
    int gcol = ((lane & 7) ^ grow) << 4;          // pre-swizzled source byte-in-row

    const char* Abp = (const char*)A + (size_t)row0 * (KT*2) + gcol;
    const char* Bbp = (const char*)B + (size_t)col0 * (KT*2) + gcol;

    // read-side constants (ushort units); row&7 == lr&7 for all frag rows
    int arow_u = (wr*128 + lr) * 64;
    int brow_u = (wc*64 + lr) * 64;
    int sa0u = ((kg ^ (lr & 7)) << 3);            // k-step 0 slot, swizzled
    int sa1u = sa0u ^ 32;                         // k-step 1 (slot+4)

    f32x4 acc[8][4] = {};

    // prologue: A0->buf0, B0->slot0, A1->buf1, B1->slot1, B2->slot2 (20 loads)
    STAGE_A2(0, 0, 0); STAGE_A2(0, 0, 1);
    STAGE_B2(0, 0, 0); STAGE_B2(0, 0, 1);
    STAGE_A2(1, 1, 0); STAGE_A2(1, 1, 1);
    STAGE_B2(1, 1, 0); STAGE_B2(1, 1, 1);
    STAGE_B2(2, 2, 0); STAGE_B2(2, 2, 1);
    asm volatile("s_waitcnt vmcnt(12)" : : : "memory");   // A0,B0 landed
    BAR();

#pragma unroll
    for (int i = 0; i < 4; ++i) {
        const int t = 2 * i;
        const int sb0 = t % 3, sb1 = (t + 1) % 3, sb2 = (t + 2) % 3, sb3 = (t + 3) % 3;
        // tile t (Abuf0, Bslot sb0); issue A(t+1) ph1-2 (i>=1: i==0 prologued),
        // B(t+2) ph3-4; wait -> A(t+1),B(t+1) landed, 4 youngest stay in flight
        KTILE(0, 16384*2 + sb0 * 16384,
              if (i >= 1) STAGE_A2(t + 1, 1, 0),
              if (i >= 1) STAGE_A2(t + 1, 1, 1),
              if (i <= 2) STAGE_B2(t + 2, sb2, 0),
              if (i <= 2) STAGE_B2(t + 2, sb2, 1),
              if (i <= 2) { asm volatile("s_waitcnt vmcnt(4)" : : : "memory"); }
              else        { asm volatile("s_waitcnt vmcnt(0)" : : : "memory"); });
        // tile t+1 (Abuf1, Bslot sb1); issue A(t+2) ph5-6, B(t+3) ph7-8
        KTILE(16384, 16384*2 + sb1 * 16384,
              if (i <= 2) STAGE_A2(t + 2, 0, 0),
              if (i <= 2) STAGE_A2(t + 2, 0, 1),
              if (i <= 2) STAGE_B2(t + 3, sb3, 0),
              if (i <= 2) STAGE_B2(t + 3, sb3, 1),
              if (i <= 2) { asm volatile("s_waitcnt vmcnt(4)" : : : "memory"); });
    }

    // epilogue: D col = lane&15, row = (lane>>4)*4 + q  (m89-verified mapping)
#pragma unroll
    for (int j = 0; j < 4; ++j) {
        int c = col0 + wc * 64 + j * 16 + lr;
        float tmc = tmv[c];
#pragma unroll
        for (int ii = 0; ii < 8; ++ii) {
            size_t r = (size_t)row0 + wr * 128 + ii * 16 + kg * 4;
            float* op = out + r * MM + c;
#pragma unroll
            for (int q = 0; q < 4; ++q)
                op[(size_t)q * MM] = __expf(-0.5f * (acc[ii][j][q] + tmc));
        }
    }
}

// ws-too-small safety net: naive fp32, correct but slow
__global__ void fallback_kernel(const float* __restrict__ x, const float* __restrict__ mu,
                                const float* __restrict__ cov, float* __restrict__ out) {
    __shared__ float xs[DD];
    int n = blockIdx.x;
    int tid = threadIdx.x;
    if (tid < 64) {
        float4 v = *(const float4*)(x + (size_t)n * DD + tid * 4);
        *(float4*)&xs[tid * 4] = v;
    }
    __syncthreads();
    for (int m = tid; m < MM; m += 256) {
        const float* mup = mu + (size_t)m * DD;
        const float* cvp = cov + (size_t)m * DD;
        float acc = 0.f;
        for (int d = 0; d < DD; ++d) {
            float v = xs[d] - mup[d];
            acc += v * v * (1.0f / cvp[d]);
        }
        out[(size_t)n * MM + m] = __expf(-0.5f * acc);
    }
}

extern "C" void kernel_launch(void* const* d_in, const int* in_sizes, int n_in,
                              void* d_out, int out_size, void* d_ws, size_t ws_size,
                              hipStream_t stream) {
    const float* x   = (const float*)d_in[0];
    const float* mu  = (const float*)d_in[1];
    const float* cov = (const float*)d_in[2];
    float* out = (float*)d_out;

    size_t needA = (size_t)NN * KT * 2;   // 64 MB
    size_t needB = (size_t)MM * KT * 2;   // 1 MB
    size_t needT = (size_t)MM * 4;        // 4 KB
    if (ws_size < needA + needB + needT) {
        fallback_kernel<<<NN, 256, 0, stream>>>(x, mu, cov, out);
        return;
    }
    unsigned short* Ab = (unsigned short*)d_ws;
    unsigned short* Bb = (unsigned short*)((char*)d_ws + needA);
    float* tmv = (float*)((char*)d_ws + needA + needB);

    prep_a_kernel<<<NN * 32 / 256, 256, 0, stream>>>(x, Ab);
    prep_b_kernel<<<MM * 64 / 256, 256, 0, stream>>>(mu, cov, Bb, tmv);
    gemm_kernel<<<(NN / BM) * (MM / BN), 512, 0, stream>>>(Ab, Bb, tmv, out);
}